// Round 1
// baseline (427.980 us; speedup 1.0000x reference)
//
#include <hip/hip_runtime.h>

#define LLEN 16384

typedef short bf16x8 __attribute__((ext_vector_type(8)));
typedef float f32x4 __attribute__((ext_vector_type(4)));

__device__ __forceinline__ short f2bf(float f) {
  union { float f; unsigned u; } v; v.f = f;
  unsigned r = (v.u + 0x7FFFu + ((v.u >> 16) & 1u)) >> 16;
  return (short)r;
}
__device__ __forceinline__ float bf2f(short s) {
  union { unsigned u; float f; } v;
  v.u = ((unsigned)(unsigned short)s) << 16;
  return v.f;
}
__device__ __forceinline__ float geluf(float x) {
  return 0.5f * x * (1.0f + erff(x * 0.70710678118654752f));
}
__device__ __forceinline__ float waveRedSum(float v) {
  #pragma unroll
  for (int o = 32; o > 0; o >>= 1) v += __shfl_xor(v, o, 64);
  return v;
}
__device__ __forceinline__ float waveRedMax(float v) {
  #pragma unroll
  for (int o = 32; o > 0; o >>= 1) v = fmaxf(v, __shfl_xor(v, o, 64));
  return v;
}

// ---------------- K0: weights -> bf16, zero rowsum ----------------
__global__ __launch_bounds__(256) void k0_convert(
    const float* __restrict__ qw, const float* __restrict__ vw,
    const float* __restrict__ gw, const float* __restrict__ mw,
    short* __restrict__ qwb, short* __restrict__ vwb,
    short* __restrict__ gwb, short* __restrict__ mwb,
    float* __restrict__ rowsum) {
  int idx = blockIdx.x * 256 + threadIdx.x;  // 65536 threads
  qwb[idx] = f2bf(qw[idx]);
  vwb[idx] = f2bf(vw[idx]);
  mwb[idx] = f2bf(mw[idx]);
  if (idx < 4096) {
    int r = idx >> 8, c = idx & 255;
    gwb[idx] = (r < 4) ? f2bf(gw[r * 256 + c]) : (short)0;
  }
  if (idx < 2048) rowsum[idx] = 0.f;
}

// 64x64-per-wave GEMM over K=256 from LDS tile xs[l][c] (bf16, padded 264)
__device__ __forceinline__ void gemm64(const short* __restrict__ wmat,
                                       const short xs[64][264], int lane,
                                       f32x4 acc[4][4]) {
  int r = lane & 15, h = lane >> 4;
  #pragma unroll
  for (int k0 = 0; k0 < 256; k0 += 32) {
    bf16x8 bfr[4];
    #pragma unroll
    for (int lf = 0; lf < 4; ++lf)
      bfr[lf] = *(const bf16x8*)&xs[lf * 16 + r][k0 + 8 * h];
    #pragma unroll
    for (int ef = 0; ef < 4; ++ef) {
      bf16x8 afr = *(const bf16x8*)(wmat + (ef * 16 + r) * 256 + k0 + 8 * h);
      #pragma unroll
      for (int lf = 0; lf < 4; ++lf)
        acc[ef][lf] = __builtin_amdgcn_mfma_f32_16x16x32_bf16(afr, bfr[lf],
                                                              acc[ef][lf], 0, 0, 0);
    }
  }
}

// ---------------- K1: focus0 = v_w@x+v_b (bf16), sigq = sigmoid(q_w@x+q_b),
//                      gates = g_w@x+g_b ----------------
__global__ __launch_bounds__(256) void k1_qvg(
    const float* __restrict__ x, const short* __restrict__ vwb,
    const short* __restrict__ qwb, const short* __restrict__ gwb,
    const float* __restrict__ v_b, const float* __restrict__ q_b,
    const float* __restrict__ g_b, short* __restrict__ focus0,
    float* __restrict__ sigq, float* __restrict__ gates) {
  int b = blockIdx.x >> 8, lt = blockIdx.x & 255;
  int l0 = lt << 6;
  __shared__ short xs[64][264];
  int t = threadIdx.x;
  {
    int l = t & 63, cg = t >> 6;
    const float* xb = x + ((size_t)b << 22) + l0 + l;
    #pragma unroll 4
    for (int rep = 0; rep < 32; ++rep) {
      int c = rep * 8 + cg * 2;
      float a0 = xb[(size_t)c << 14];
      float a1 = xb[((size_t)c + 1) << 14];
      unsigned pk = (unsigned)(unsigned short)f2bf(a0) |
                    ((unsigned)(unsigned short)f2bf(a1) << 16);
      *(unsigned*)&xs[l][c] = pk;
    }
  }
  __syncthreads();
  int lane = t & 63, wave = t >> 6;
  int r = lane & 15, h = lane >> 4;
  int e0 = wave << 6;
  f32x4 acc[4][4];

  // ---- V GEMM -> focus0 (bf16)
  #pragma unroll
  for (int ef = 0; ef < 4; ++ef)
    #pragma unroll
    for (int lf = 0; lf < 4; ++lf)
      acc[ef][lf] = (f32x4){0.f, 0.f, 0.f, 0.f};
  gemm64(vwb + e0 * 256, xs, lane, acc);
  #pragma unroll
  for (int ef = 0; ef < 4; ++ef) {
    #pragma unroll
    for (int i = 0; i < 4; ++i) {
      int e = e0 + ef * 16 + 4 * h + i;
      float bias = v_b[e];
      size_t rowoff = (size_t)((b << 8) | e) << 14;
      #pragma unroll
      for (int lf = 0; lf < 4; ++lf) {
        int li = l0 + lf * 16 + r;
        focus0[rowoff + li] = f2bf(acc[ef][lf][i] + bias);
      }
    }
  }

  // ---- Q GEMM -> sigq (f32, lives in out-region)
  #pragma unroll
  for (int ef = 0; ef < 4; ++ef)
    #pragma unroll
    for (int lf = 0; lf < 4; ++lf)
      acc[ef][lf] = (f32x4){0.f, 0.f, 0.f, 0.f};
  gemm64(qwb + e0 * 256, xs, lane, acc);
  #pragma unroll
  for (int ef = 0; ef < 4; ++ef) {
    #pragma unroll
    for (int i = 0; i < 4; ++i) {
      int e = e0 + ef * 16 + 4 * h + i;
      float bias = q_b[e];
      size_t rowoff = (size_t)((b << 8) | e) << 14;
      #pragma unroll
      for (int lf = 0; lf < 4; ++lf) {
        int li = l0 + lf * 16 + r;
        float z = acc[ef][lf][i] + bias;
        sigq[rowoff + li] = 1.0f / (1.0f + expf(-z));
      }
    }
  }

  // ---- gates: 4x256 GEMM on wave 0 only (16-row padded tile)
  if (wave == 0) {
    f32x4 gacc[4];
    #pragma unroll
    for (int lf = 0; lf < 4; ++lf) gacc[lf] = (f32x4){0.f, 0.f, 0.f, 0.f};
    #pragma unroll
    for (int k0 = 0; k0 < 256; k0 += 32) {
      bf16x8 afr = *(const bf16x8*)(gwb + r * 256 + k0 + 8 * h);
      #pragma unroll
      for (int lf = 0; lf < 4; ++lf) {
        bf16x8 bfr = *(const bf16x8*)&xs[lf * 16 + r][k0 + 8 * h];
        gacc[lf] = __builtin_amdgcn_mfma_f32_16x16x32_bf16(afr, bfr, gacc[lf], 0, 0, 0);
      }
    }
    if (h == 0) {  // lanes 0..15 hold rows 0..3 (i = row)
      #pragma unroll
      for (int i = 0; i < 4; ++i) {
        float gb = g_b[i];
        size_t goff = (size_t)((b << 2) | i) << 14;
        #pragma unroll
        for (int lf = 0; lf < 4; ++lf)
          gates[goff + l0 + lf * 16 + r] = gacc[lf][i] + gb;
      }
    }
  }
}

// ---------------- K2: fused 3-level depthwise conv + gelu chain,
//                      acc3 -> mask region, rowsum(f3) atomics ----------------
__global__ __launch_bounds__(256) void k2_conv(
    const short* __restrict__ focus0, const float* __restrict__ gates,
    const float* __restrict__ f0_w, const float* __restrict__ f1_w,
    const float* __restrict__ f2_w, float* __restrict__ acc3,
    float* __restrict__ rowsum) {
  int bx = blockIdx.x;
  int b = bx >> 12, c = (bx >> 4) & 255, lt = bx & 15;
  int l0 = lt << 10;
  __shared__ float s0[1036], s1[1034], s2[1030];
  __shared__ float rs[4];
  int t = threadIdx.x;
  const short* fp = focus0 + ((size_t)((b << 8) | c) << 14);
  for (int i = t; i < 1036; i += 256) {
    int gl = l0 - 6 + i;
    s0[i] = (gl >= 0 && gl < LLEN) ? bf2f(fp[gl]) : 0.f;
  }
  float w0[3], w1[5], w2[7];
  #pragma unroll
  for (int j = 0; j < 3; ++j) w0[j] = f0_w[c * 3 + j];
  #pragma unroll
  for (int j = 0; j < 5; ++j) w1[j] = f1_w[c * 5 + j];
  #pragma unroll
  for (int j = 0; j < 7; ++j) w2[j] = f2_w[c * 7 + j];
  __syncthreads();
  for (int i = t; i < 1034; i += 256) {
    int gl = l0 - 5 + i;
    float z = w0[0] * s0[i] + w0[1] * s0[i + 1] + w0[2] * s0[i + 2];
    s1[i] = (gl >= 0 && gl < LLEN) ? geluf(z) : 0.f;
  }
  __syncthreads();
  for (int i = t; i < 1030; i += 256) {
    int gl = l0 - 3 + i;
    float z = w1[0] * s1[i] + w1[1] * s1[i + 1] + w1[2] * s1[i + 2] +
              w1[3] * s1[i + 3] + w1[4] * s1[i + 4];
    s2[i] = (gl >= 0 && gl < LLEN) ? geluf(z) : 0.f;
  }
  __syncthreads();
  const float* gp = gates + ((size_t)(b << 2) << 14);
  float* op = acc3 + ((size_t)((b << 8) | c) << 14);
  float lsum = 0.f;
  for (int i = t; i < 1024; i += 256) {
    float z = w2[0] * s2[i] + w2[1] * s2[i + 1] + w2[2] * s2[i + 2] +
              w2[3] * s2[i + 3] + w2[4] * s2[i + 4] + w2[5] * s2[i + 5] +
              w2[6] * s2[i + 6];
    float f3 = geluf(z);
    lsum += f3;
    int l = l0 + i;
    float a = s1[i + 5] * gp[l] + s2[i + 3] * gp[LLEN + l] + f3 * gp[2 * LLEN + l];
    op[l] = a;
  }
  float wsv = waveRedSum(lsum);
  if ((t & 63) == 0) rs[t >> 6] = wsv;
  __syncthreads();
  if (t == 0) atomicAdd(&rowsum[(b << 8) | c], rs[0] + rs[1] + rs[2] + rs[3]);
}

// ---------------- K3: global focus = gelu(mean) ----------------
__global__ __launch_bounds__(256) void k3_gf(const float* __restrict__ rowsum,
                                             float* __restrict__ gf) {
  int i = blockIdx.x * 256 + threadIdx.x;
  gf[i] = geluf(rowsum[i] * (1.0f / 16384.0f));
}

// ---------------- K4: m = mix_w @ (acc3 + gf*g3) + mix_b, in place ----------------
__global__ __launch_bounds__(256) void k4_mix(
    float* mbuf, const float* __restrict__ gates, const float* __restrict__ gf,
    const short* __restrict__ mwb, const float* __restrict__ mix_b) {
  int b = blockIdx.x >> 8, lt = blockIdx.x & 255;
  int l0 = lt << 6;
  __shared__ short xs[64][264];
  int t = threadIdx.x;
  {
    int l = t & 63, cg = t >> 6;
    float g3 = gates[((size_t)((b << 2) | 3) << 14) + l0 + l];
    const float* ap = mbuf + ((size_t)b << 22) + l0 + l;
    const float* gfp = gf + (b << 8);
    #pragma unroll 4
    for (int rep = 0; rep < 32; ++rep) {
      int c = rep * 8 + cg * 2;
      float a0 = ap[(size_t)c << 14] + gfp[c] * g3;
      float a1 = ap[((size_t)c + 1) << 14] + gfp[c + 1] * g3;
      unsigned pk = (unsigned)(unsigned short)f2bf(a0) |
                    ((unsigned)(unsigned short)f2bf(a1) << 16);
      *(unsigned*)&xs[l][c] = pk;
    }
  }
  __syncthreads();
  int lane = t & 63, wave = t >> 6;
  int r = lane & 15, h = lane >> 4;
  int e0 = wave << 6;
  f32x4 acc[4][4];
  #pragma unroll
  for (int ef = 0; ef < 4; ++ef)
    #pragma unroll
    for (int lf = 0; lf < 4; ++lf)
      acc[ef][lf] = (f32x4){0.f, 0.f, 0.f, 0.f};
  gemm64(mwb + e0 * 256, xs, lane, acc);
  #pragma unroll
  for (int ef = 0; ef < 4; ++ef) {
    #pragma unroll
    for (int i = 0; i < 4; ++i) {
      int o = e0 + ef * 16 + 4 * h + i;
      float bias = mix_b[o];
      size_t rowoff = (size_t)((b << 8) | o) << 14;
      #pragma unroll
      for (int lf = 0; lf < 4; ++lf) {
        int li = l0 + lf * 16 + r;
        mbuf[rowoff + li] = acc[ef][lf][i] + bias;
      }
    }
  }
}

// ---------------- K5: per-row softmax over L; out = sigq * mask ----------------
__global__ __launch_bounds__(256) void k5_softmax(float* __restrict__ mrowbuf,
                                                  float* __restrict__ orowbuf) {
  int row = blockIdx.x;  // b*256 + o
  float* mrow = mrowbuf + ((size_t)row << 14);
  float* orow = orowbuf + ((size_t)row << 14);
  int t = threadIdx.x;
  int lane = t & 63, wave = t >> 6;
  float4 v[16];
  float lm = -3.0e38f;
  #pragma unroll
  for (int i = 0; i < 16; ++i) {
    v[i] = *(const float4*)&mrow[i * 1024 + t * 4];
    lm = fmaxf(lm, fmaxf(fmaxf(v[i].x, v[i].y), fmaxf(v[i].z, v[i].w)));
  }
  __shared__ float redm[4], reds[4];
  float wm = waveRedMax(lm);
  if (lane == 0) redm[wave] = wm;
  __syncthreads();
  float M = fmaxf(fmaxf(redm[0], redm[1]), fmaxf(redm[2], redm[3]));
  float ls = 0.f;
  #pragma unroll
  for (int i = 0; i < 16; ++i) {
    v[i].x = expf(v[i].x - M);
    v[i].y = expf(v[i].y - M);
    v[i].z = expf(v[i].z - M);
    v[i].w = expf(v[i].w - M);
    ls += (v[i].x + v[i].y) + (v[i].z + v[i].w);
  }
  float wsum = waveRedSum(ls);
  if (lane == 0) reds[wave] = wsum;
  __syncthreads();
  float S = reds[0] + reds[1] + reds[2] + reds[3];
  float inv = 1.0f / S;
  #pragma unroll
  for (int i = 0; i < 16; ++i) {
    float4 mk;
    mk.x = v[i].x * inv; mk.y = v[i].y * inv;
    mk.z = v[i].z * inv; mk.w = v[i].w * inv;
    *(float4*)&mrow[i * 1024 + t * 4] = mk;
    float4 sq = *(const float4*)&orow[i * 1024 + t * 4];
    sq.x *= mk.x; sq.y *= mk.y; sq.z *= mk.z; sq.w *= mk.w;
    *(float4*)&orow[i * 1024 + t * 4] = sq;
  }
}

extern "C" void kernel_launch(void* const* d_in, const int* in_sizes, int n_in,
                              void* d_out, int out_size, void* d_ws, size_t ws_size,
                              hipStream_t stream) {
  const float* x     = (const float*)d_in[0];
  const float* q_w   = (const float*)d_in[1];
  const float* q_b   = (const float*)d_in[2];
  const float* v_w   = (const float*)d_in[3];
  const float* v_b   = (const float*)d_in[4];
  const float* g_w   = (const float*)d_in[5];
  const float* g_b   = (const float*)d_in[6];
  const float* f0_w  = (const float*)d_in[7];
  const float* f1_w  = (const float*)d_in[8];
  const float* f2_w  = (const float*)d_in[9];
  const float* mix_w = (const float*)d_in[10];
  const float* mix_b = (const float*)d_in[11];

  float* outbuf  = (float*)d_out;                       // out [8,256,16384]
  float* maskbuf = outbuf + (size_t)8 * 256 * 16384;    // mask [8,256,16384]

  char* ws = (char*)d_ws;
  short* vwb    = (short*)(ws + 0);        // 131072 B
  short* qwb    = (short*)(ws + 131072);   // 131072 B
  short* mwb    = (short*)(ws + 262144);   // 131072 B
  short* gwb    = (short*)(ws + 393216);   // 8192 B (16x256 bf16, rows>=4 zero)
  float* rowsum = (float*)(ws + 401408);   // 8192 B
  float* gf     = (float*)(ws + 409600);   // 8192 B
  float* gates  = (float*)(ws + 417792);   // 8*4*16384*4 = 2097152 B
  short* focus0 = (short*)(ws + 2514944);  // 8*256*16384*2 = 67108864 B

  k0_convert<<<dim3(256), dim3(256), 0, stream>>>(q_w, v_w, g_w, mix_w,
                                                  qwb, vwb, gwb, mwb, rowsum);
  k1_qvg<<<dim3(2048), dim3(256), 0, stream>>>(x, vwb, qwb, gwb, v_b, q_b, g_b,
                                               focus0, outbuf, gates);
  k2_conv<<<dim3(32768), dim3(256), 0, stream>>>(focus0, gates, f0_w, f1_w, f2_w,
                                                 maskbuf, rowsum);
  k3_gf<<<dim3(8), dim3(256), 0, stream>>>(rowsum, gf);
  k4_mix<<<dim3(2048), dim3(256), 0, stream>>>(maskbuf, gates, gf, mwb, mix_b);
  k5_softmax<<<dim3(2048), dim3(256), 0, stream>>>(maskbuf, outbuf);
}

// Round 2
// 363.928 us; speedup vs baseline: 1.1760x; 1.1760x over previous
//
#include <hip/hip_runtime.h>

#define LLEN 16384
#define PAD 258  // 516B row stride = 129 dwords; 129%32==1 -> 2-way (free) LDS aliasing

typedef short bf16x8 __attribute__((ext_vector_type(8)));
typedef float f32x4 __attribute__((ext_vector_type(4)));

__device__ __forceinline__ short f2bf(float f) {
  union { float f; unsigned u; } v; v.f = f;
  unsigned r = (v.u + 0x7FFFu + ((v.u >> 16) & 1u)) >> 16;
  return (short)r;
}
__device__ __forceinline__ float bf2f(short s) {
  union { unsigned u; float f; } v;
  v.u = ((unsigned)(unsigned short)s) << 16;
  return v.f;
}
__device__ __forceinline__ float geluf(float x) {
  return 0.5f * x * (1.0f + erff(x * 0.70710678118654752f));
}
__device__ __forceinline__ float waveRedSum(float v) {
  #pragma unroll
  for (int o = 32; o > 0; o >>= 1) v += __shfl_xor(v, o, 64);
  return v;
}
__device__ __forceinline__ float waveRedMax(float v) {
  #pragma unroll
  for (int o = 32; o > 0; o >>= 1) v = fmaxf(v, __shfl_xor(v, o, 64));
  return v;
}

// ---------------- K0: weights -> bf16, zero rowsum ----------------
__global__ __launch_bounds__(256) void k0_convert(
    const float* __restrict__ qw, const float* __restrict__ vw,
    const float* __restrict__ gw, const float* __restrict__ mw,
    short* __restrict__ qwb, short* __restrict__ vwb,
    short* __restrict__ gwb, short* __restrict__ mwb,
    float* __restrict__ rowsum) {
  int idx = blockIdx.x * 256 + threadIdx.x;  // 65536 threads
  qwb[idx] = f2bf(qw[idx]);
  vwb[idx] = f2bf(vw[idx]);
  mwb[idx] = f2bf(mw[idx]);
  if (idx < 4096) {
    int r = idx >> 8, c = idx & 255;
    gwb[idx] = (r < 4) ? f2bf(gw[r * 256 + c]) : (short)0;
  }
  if (idx < 2048) rowsum[idx] = 0.f;
}

// 64x64-per-wave GEMM over K=256 from LDS tile xs[l][c] (bf16, padded PAD)
__device__ __forceinline__ void gemm64(const short* __restrict__ wmat,
                                       const short xs[64][PAD], int lane,
                                       f32x4 acc[4][4]) {
  int r = lane & 15, h = lane >> 4;
  #pragma unroll
  for (int k0 = 0; k0 < 256; k0 += 32) {
    bf16x8 bfr[4];
    #pragma unroll
    for (int lf = 0; lf < 4; ++lf)
      bfr[lf] = *(const bf16x8*)&xs[lf * 16 + r][k0 + 8 * h];
    #pragma unroll
    for (int ef = 0; ef < 4; ++ef) {
      bf16x8 afr = *(const bf16x8*)(wmat + (ef * 16 + r) * 256 + k0 + 8 * h);
      #pragma unroll
      for (int lf = 0; lf < 4; ++lf)
        acc[ef][lf] = __builtin_amdgcn_mfma_f32_16x16x32_bf16(afr, bfr[lf],
                                                              acc[ef][lf], 0, 0, 0);
    }
  }
}

// ---------------- K1: focus0 = v_w@x+v_b (bf16), qz = q_w@x+q_b (bf16),
//                      gates = g_w@x+g_b ----------------
// qz row e goes to upper 32KiB of out-region f32 row e (race-free scratch).
__global__ __launch_bounds__(256) void k1_qvg(
    const float* __restrict__ x, const short* __restrict__ vwb,
    const short* __restrict__ qwb, const short* __restrict__ gwb,
    const float* __restrict__ v_b, const float* __restrict__ q_b,
    const float* __restrict__ g_b, short* __restrict__ focus0,
    short* __restrict__ qzS, float* __restrict__ gates) {
  int b = blockIdx.x >> 8, lt = blockIdx.x & 255;
  int l0 = lt << 6;
  __shared__ short xs[64][PAD];
  int t = threadIdx.x;
  {
    int l = t & 63, cg = t >> 6;
    const float* xb = x + ((size_t)b << 22) + l0 + l;
    #pragma unroll 4
    for (int rep = 0; rep < 32; ++rep) {
      int c = rep * 8 + cg * 2;
      float a0 = xb[(size_t)c << 14];
      float a1 = xb[((size_t)c + 1) << 14];
      unsigned pk = (unsigned)(unsigned short)f2bf(a0) |
                    ((unsigned)(unsigned short)f2bf(a1) << 16);
      *(unsigned*)&xs[l][c] = pk;
    }
  }
  __syncthreads();
  int lane = t & 63, wave = t >> 6;
  int r = lane & 15, h = lane >> 4;
  int e0 = wave << 6;
  f32x4 acc[4][4];

  // ---- V GEMM -> focus0 (bf16)
  #pragma unroll
  for (int ef = 0; ef < 4; ++ef)
    #pragma unroll
    for (int lf = 0; lf < 4; ++lf)
      acc[ef][lf] = (f32x4){0.f, 0.f, 0.f, 0.f};
  gemm64(vwb + e0 * 256, xs, lane, acc);
  #pragma unroll
  for (int ef = 0; ef < 4; ++ef) {
    #pragma unroll
    for (int i = 0; i < 4; ++i) {
      int e = e0 + ef * 16 + 4 * h + i;
      float bias = v_b[e];
      size_t rowoff = (size_t)((b << 8) | e) << 14;
      #pragma unroll
      for (int lf = 0; lf < 4; ++lf) {
        int li = l0 + lf * 16 + r;
        focus0[rowoff + li] = f2bf(acc[ef][lf][i] + bias);
      }
    }
  }

  // ---- Q GEMM -> qz (bf16, interleaved in out region; sigmoid deferred to K5)
  #pragma unroll
  for (int ef = 0; ef < 4; ++ef)
    #pragma unroll
    for (int lf = 0; lf < 4; ++lf)
      acc[ef][lf] = (f32x4){0.f, 0.f, 0.f, 0.f};
  gemm64(qwb + e0 * 256, xs, lane, acc);
  #pragma unroll
  for (int ef = 0; ef < 4; ++ef) {
    #pragma unroll
    for (int i = 0; i < 4; ++i) {
      int e = e0 + ef * 16 + 4 * h + i;
      float bias = q_b[e];
      size_t rowoff = ((size_t)((b << 8) | e) << 15) + 16384;
      #pragma unroll
      for (int lf = 0; lf < 4; ++lf) {
        int li = l0 + lf * 16 + r;
        qzS[rowoff + li] = f2bf(acc[ef][lf][i] + bias);
      }
    }
  }

  // ---- gates: 4x256 GEMM on wave 0 only (16-row padded tile)
  if (wave == 0) {
    f32x4 gacc[4];
    #pragma unroll
    for (int lf = 0; lf < 4; ++lf) gacc[lf] = (f32x4){0.f, 0.f, 0.f, 0.f};
    #pragma unroll
    for (int k0 = 0; k0 < 256; k0 += 32) {
      bf16x8 afr = *(const bf16x8*)(gwb + r * 256 + k0 + 8 * h);
      #pragma unroll
      for (int lf = 0; lf < 4; ++lf) {
        bf16x8 bfr = *(const bf16x8*)&xs[lf * 16 + r][k0 + 8 * h];
        gacc[lf] = __builtin_amdgcn_mfma_f32_16x16x32_bf16(afr, bfr, gacc[lf], 0, 0, 0);
      }
    }
    if (h == 0) {  // lanes 0..15 hold rows 0..3 (i = row)
      #pragma unroll
      for (int i = 0; i < 4; ++i) {
        float gb = g_b[i];
        size_t goff = (size_t)((b << 2) | i) << 14;
        #pragma unroll
        for (int lf = 0; lf < 4; ++lf)
          gates[goff + l0 + lf * 16 + r] = gacc[lf][i] + gb;
      }
    }
  }
}

// ---------------- K2: fused 3-level depthwise conv + gelu chain,
//                      acc3 (bf16) -> lower half of mask rows; rowsum atomics ----
__global__ __launch_bounds__(256) void k2_conv(
    const short* __restrict__ focus0, const float* __restrict__ gates,
    const float* __restrict__ f0_w, const float* __restrict__ f1_w,
    const float* __restrict__ f2_w, short* __restrict__ acc3S,
    float* __restrict__ rowsum) {
  int bx = blockIdx.x;
  int b = bx >> 12, c = (bx >> 4) & 255, lt = bx & 15;
  int l0 = lt << 10;
  __shared__ float s0[1036], s1[1034], s2[1030];
  __shared__ float rs[4];
  int t = threadIdx.x;
  const short* fp = focus0 + ((size_t)((b << 8) | c) << 14);
  for (int i = t; i < 1036; i += 256) {
    int gl = l0 - 6 + i;
    s0[i] = (gl >= 0 && gl < LLEN) ? bf2f(fp[gl]) : 0.f;
  }
  float w0[3], w1[5], w2[7];
  #pragma unroll
  for (int j = 0; j < 3; ++j) w0[j] = f0_w[c * 3 + j];
  #pragma unroll
  for (int j = 0; j < 5; ++j) w1[j] = f1_w[c * 5 + j];
  #pragma unroll
  for (int j = 0; j < 7; ++j) w2[j] = f2_w[c * 7 + j];
  __syncthreads();
  for (int i = t; i < 1034; i += 256) {
    int gl = l0 - 5 + i;
    float z = w0[0] * s0[i] + w0[1] * s0[i + 1] + w0[2] * s0[i + 2];
    s1[i] = (gl >= 0 && gl < LLEN) ? geluf(z) : 0.f;
  }
  __syncthreads();
  for (int i = t; i < 1030; i += 256) {
    int gl = l0 - 3 + i;
    float z = w1[0] * s1[i] + w1[1] * s1[i + 1] + w1[2] * s1[i + 2] +
              w1[3] * s1[i + 3] + w1[4] * s1[i + 4];
    s2[i] = (gl >= 0 && gl < LLEN) ? geluf(z) : 0.f;
  }
  __syncthreads();
  const float* gp = gates + ((size_t)(b << 2) << 14);
  short* op = acc3S + ((size_t)((b << 8) | c) << 15);  // lower 32KiB of mask row
  float lsum = 0.f;
  #pragma unroll
  for (int ii = 0; ii < 2; ++ii) {
    int i = 2 * t + 512 * ii;
    float z0 = w2[0] * s2[i] + w2[1] * s2[i + 1] + w2[2] * s2[i + 2] +
               w2[3] * s2[i + 3] + w2[4] * s2[i + 4] + w2[5] * s2[i + 5] +
               w2[6] * s2[i + 6];
    float z1 = w2[0] * s2[i + 1] + w2[1] * s2[i + 2] + w2[2] * s2[i + 3] +
               w2[3] * s2[i + 4] + w2[4] * s2[i + 5] + w2[5] * s2[i + 6] +
               w2[6] * s2[i + 7];
    float f30 = geluf(z0), f31 = geluf(z1);
    lsum += f30 + f31;
    int l = l0 + i;
    float a0 = s1[i + 5] * gp[l] + s2[i + 3] * gp[LLEN + l] + f30 * gp[2 * LLEN + l];
    float a1 = s1[i + 6] * gp[l + 1] + s2[i + 4] * gp[LLEN + l + 1] +
               f31 * gp[2 * LLEN + l + 1];
    unsigned pk = (unsigned)(unsigned short)f2bf(a0) |
                  ((unsigned)(unsigned short)f2bf(a1) << 16);
    *(unsigned*)&op[l] = pk;
  }
  float wsv = waveRedSum(lsum);
  if ((t & 63) == 0) rs[t >> 6] = wsv;
  __syncthreads();
  if (t == 0) atomicAdd(&rowsum[(b << 8) | c], rs[0] + rs[1] + rs[2] + rs[3]);
}

// ---------------- K3: global focus = gelu(mean) ----------------
__global__ __launch_bounds__(256) void k3_gf(const float* __restrict__ rowsum,
                                             float* __restrict__ gf) {
  int i = blockIdx.x * 256 + threadIdx.x;
  gf[i] = geluf(rowsum[i] * (1.0f / 16384.0f));
}

// ---------------- K4: m = mix_w @ (acc3 + gf*g3) + mix_b -> bf16 (upper half) ----
__global__ __launch_bounds__(256) void k4_mix(
    short* maskS, const float* __restrict__ gates, const float* __restrict__ gf,
    const short* __restrict__ mwb, const float* __restrict__ mix_b) {
  int b = blockIdx.x >> 8, lt = blockIdx.x & 255;
  int l0 = lt << 6;
  __shared__ short xs[64][PAD];
  int t = threadIdx.x;
  {
    int l = t & 63, cg = t >> 6;
    float g3 = gates[((size_t)((b << 2) | 3) << 14) + l0 + l];
    const float* gfp = gf + (b << 8);
    const short* ap = maskS + ((size_t)(b << 8) << 15) + l0 + l;
    #pragma unroll 4
    for (int rep = 0; rep < 32; ++rep) {
      int c = rep * 8 + cg * 2;
      float a0 = bf2f(ap[(size_t)c << 15]) + gfp[c] * g3;
      float a1 = bf2f(ap[((size_t)c + 1) << 15]) + gfp[c + 1] * g3;
      unsigned pk = (unsigned)(unsigned short)f2bf(a0) |
                    ((unsigned)(unsigned short)f2bf(a1) << 16);
      *(unsigned*)&xs[l][c] = pk;
    }
  }
  __syncthreads();
  int lane = t & 63, wave = t >> 6;
  int r = lane & 15, h = lane >> 4;
  int e0 = wave << 6;
  f32x4 acc[4][4];
  #pragma unroll
  for (int ef = 0; ef < 4; ++ef)
    #pragma unroll
    for (int lf = 0; lf < 4; ++lf)
      acc[ef][lf] = (f32x4){0.f, 0.f, 0.f, 0.f};
  gemm64(mwb + e0 * 256, xs, lane, acc);
  #pragma unroll
  for (int ef = 0; ef < 4; ++ef) {
    #pragma unroll
    for (int i = 0; i < 4; ++i) {
      int o = e0 + ef * 16 + 4 * h + i;
      float bias = mix_b[o];
      size_t rowoff = ((size_t)((b << 8) | o) << 15) + 16384;  // upper 32KiB
      #pragma unroll
      for (int lf = 0; lf < 4; ++lf) {
        int li = l0 + lf * 16 + r;
        maskS[rowoff + li] = f2bf(acc[ef][lf][i] + bias);
      }
    }
  }
}

// ---------------- K5: softmax over L from bf16 m; out = sigmoid(qz)*mask ----
__global__ __launch_bounds__(512) void k5_softmax(
    const short* __restrict__ maskS, const short* __restrict__ outS,
    float* __restrict__ maskF, float* __restrict__ outF) {
  int row = blockIdx.x;  // b*256 + o
  int t = threadIdx.x;   // 512 threads, 8 waves
  const short* mrow = maskS + ((size_t)row << 15) + 16384;
  const short* qrow = outS + ((size_t)row << 15) + 16384;
  float* mw = maskF + ((size_t)row << 14);
  float* ow = outF + ((size_t)row << 14);
  int lane = t & 63, wave = t >> 6;
  bf16x8 qv[4];
  float f[32];
  float lm = -3.0e38f;
  #pragma unroll
  for (int i = 0; i < 4; ++i) {
    bf16x8 mv = *(const bf16x8*)&mrow[i * 4096 + t * 8];
    qv[i] = *(const bf16x8*)&qrow[i * 4096 + t * 8];
    #pragma unroll
    for (int j = 0; j < 8; ++j) {
      float vf = bf2f(mv[j]);
      f[i * 8 + j] = vf;
      lm = fmaxf(lm, vf);
    }
  }
  __shared__ float redm[8], reds[8];
  float wm = waveRedMax(lm);
  if (lane == 0) redm[wave] = wm;
  __syncthreads();  // also drains all global loads (vmcnt) before any write below
  float M = redm[0];
  #pragma unroll
  for (int w = 1; w < 8; ++w) M = fmaxf(M, redm[w]);
  float ls = 0.f;
  #pragma unroll
  for (int k = 0; k < 32; ++k) {
    f[k] = expf(f[k] - M);
    ls += f[k];
  }
  float wsum = waveRedSum(ls);
  if (lane == 0) reds[wave] = wsum;
  __syncthreads();
  float S = reds[0];
  #pragma unroll
  for (int w = 1; w < 8; ++w) S += reds[w];
  float inv = 1.0f / S;
  #pragma unroll
  for (int i = 0; i < 4; ++i) {
    float mk[8], oo[8];
    #pragma unroll
    for (int j = 0; j < 8; ++j) {
      mk[j] = f[i * 8 + j] * inv;
      float sig = 1.0f / (1.0f + expf(-bf2f(qv[i][j])));
      oo[j] = sig * mk[j];
    }
    float* mp = &mw[i * 4096 + t * 8];
    float* op = &ow[i * 4096 + t * 8];
    *(float4*)mp = (float4){mk[0], mk[1], mk[2], mk[3]};
    *(float4*)(mp + 4) = (float4){mk[4], mk[5], mk[6], mk[7]};
    *(float4*)op = (float4){oo[0], oo[1], oo[2], oo[3]};
    *(float4*)(op + 4) = (float4){oo[4], oo[5], oo[6], oo[7]};
  }
}

extern "C" void kernel_launch(void* const* d_in, const int* in_sizes, int n_in,
                              void* d_out, int out_size, void* d_ws, size_t ws_size,
                              hipStream_t stream) {
  const float* x     = (const float*)d_in[0];
  const float* q_w   = (const float*)d_in[1];
  const float* q_b   = (const float*)d_in[2];
  const float* v_w   = (const float*)d_in[3];
  const float* v_b   = (const float*)d_in[4];
  const float* g_w   = (const float*)d_in[5];
  const float* g_b   = (const float*)d_in[6];
  const float* f0_w  = (const float*)d_in[7];
  const float* f1_w  = (const float*)d_in[8];
  const float* f2_w  = (const float*)d_in[9];
  const float* mix_w = (const float*)d_in[10];
  const float* mix_b = (const float*)d_in[11];

  float* outbuf  = (float*)d_out;                       // out [8,256,16384] f32
  float* maskbuf = outbuf + (size_t)8 * 256 * 16384;    // mask [8,256,16384] f32
  short* outS  = (short*)outbuf;   // per-row: [32KiB out f32][32KiB qz bf16]
  short* maskS = (short*)maskbuf;  // per-row: [32KiB acc3 bf16][32KiB m bf16]

  char* ws = (char*)d_ws;
  short* vwb    = (short*)(ws + 0);        // 131072 B
  short* qwb    = (short*)(ws + 131072);   // 131072 B
  short* mwb    = (short*)(ws + 262144);   // 131072 B
  short* gwb    = (short*)(ws + 393216);   // 8192 B (16x256 bf16, rows>=4 zero)
  float* rowsum = (float*)(ws + 401408);   // 8192 B
  float* gf     = (float*)(ws + 409600);   // 8192 B
  float* gates  = (float*)(ws + 417792);   // 2097152 B
  short* focus0 = (short*)(ws + 2514944);  // 67108864 B

  k0_convert<<<dim3(256), dim3(256), 0, stream>>>(q_w, v_w, g_w, mix_w,
                                                  qwb, vwb, gwb, mwb, rowsum);
  k1_qvg<<<dim3(2048), dim3(256), 0, stream>>>(x, vwb, qwb, gwb, v_b, q_b, g_b,
                                               focus0, outS, gates);
  k2_conv<<<dim3(32768), dim3(256), 0, stream>>>(focus0, gates, f0_w, f1_w, f2_w,
                                                 maskS, rowsum);
  k3_gf<<<dim3(8), dim3(256), 0, stream>>>(rowsum, gf);
  k4_mix<<<dim3(2048), dim3(256), 0, stream>>>(maskS, gates, gf, mwb, mix_b);
  k5_softmax<<<dim3(2048), dim3(512), 0, stream>>>(maskS, outS, maskbuf, outbuf);
}